// Round 11
// baseline (22896.463 us; speedup 1.0000x reference)
//
#include <hip/hip_runtime.h>
#include <hip/hip_bf16.h>
#include <stdint.h>
#include <math.h>

// Problem dims
constexpr int SEQ  = 4096;
constexpr int DIN  = 1152;
constexpr int HID  = 512;
constexpr int G4H  = 2048;   // 4*HID
constexpr int KTAG = 24;
constexpr float NEGV = -10000.0f;

__device__ __forceinline__ float sigm(float x) { return 1.0f / (1.0f + expf(-x)); }

// =====================================================================
// GEMM: C[SEQ][2048] = A[SEQ][KA] @ W[2048][KA]^T + b   (fp32, 128x128 tile,
// 8x8 per thread, K-step 16, DOUBLE-BUFFERED LDS: one barrier per K-slab,
// global loads for slab k+1 issued under compute of slab k).
// Per-element accumulation is a single fmaf chain in strictly ascending k
// with bias added last -> BIT-EXACT with the original tiling (absmax 0.0).
// =====================================================================
__global__ __launch_bounds__(256) void gemm_proj(
    const float* __restrict__ A, const float* __restrict__ hf, const float* __restrict__ hb,
    int KA, int mode,
    const float* __restrict__ Wf, const float* __restrict__ bf, float* __restrict__ Cf,
    const float* __restrict__ Wb, const float* __restrict__ bb, float* __restrict__ Cb)
{
    const float* W    = blockIdx.z ? Wb : Wf;
    const float* bias = blockIdx.z ? bb : bf;
    float*       C    = blockIdx.z ? Cb : Cf;

    __shared__ __align__(16) float As[2][16][132];   // [buf][k][m], pad 132
    __shared__ __align__(16) float Ws[2][16][144];   // [buf][k][pos(n)], bank-spread

    const int tid  = threadIdx.x;
    const int bm   = blockIdx.x * 128;
    const int bn   = blockIdx.y * 128;
    const int lrow = tid >> 1;            // 0..127
    const int kq   = (tid & 1) * 8;       // 0 or 8
    const int tx   = tid & 15;            // col block (8 wide)
    const int ty   = tid >> 4;            // row block (8 tall)
    const int wpos = lrow + 4 * (lrow >> 5);        // Ws write position
    const int bpos = tx * 8 + 4 * (tx >> 2);        // Ws read position

    float acc[8][8] = {};
    float4 a0, a1, w0, w1;

    // load slab 0 into registers
    {
        const int k0 = kq;
        if (mode == 0) {
            const float* p = A + (size_t)(bm + lrow) * KA + k0;
            a0 = *(const float4*)p; a1 = *(const float4*)(p + 4);
        } else {
            const int arow = bm + lrow;
            const float* p0 = (k0 < 512) ? (hf + (size_t)(arow + 1) * HID + k0)
                                         : (hb + (size_t)(SEQ - arow) * HID + (k0 - 512));
            const int k1 = k0 + 4;
            const float* p1 = (k1 < 512) ? (hf + (size_t)(arow + 1) * HID + k1)
                                         : (hb + (size_t)(SEQ - arow) * HID + (k1 - 512));
            a0 = *(const float4*)p0; a1 = *(const float4*)p1;
        }
        const float* qp = W + (size_t)(bn + lrow) * KA + k0;
        w0 = *(const float4*)qp; w1 = *(const float4*)(qp + 4);
    }

    int buf = 0;
    for (int bk = 0; bk < KA; bk += 16) {
        // stage current slab regs -> LDS[buf]
        As[buf][kq+0][lrow] = a0.x; As[buf][kq+1][lrow] = a0.y; As[buf][kq+2][lrow] = a0.z; As[buf][kq+3][lrow] = a0.w;
        As[buf][kq+4][lrow] = a1.x; As[buf][kq+5][lrow] = a1.y; As[buf][kq+6][lrow] = a1.z; As[buf][kq+7][lrow] = a1.w;
        Ws[buf][kq+0][wpos] = w0.x; Ws[buf][kq+1][wpos] = w0.y; Ws[buf][kq+2][wpos] = w0.z; Ws[buf][kq+3][wpos] = w0.w;
        Ws[buf][kq+4][wpos] = w1.x; Ws[buf][kq+5][wpos] = w1.y; Ws[buf][kq+6][wpos] = w1.z; Ws[buf][kq+7][wpos] = w1.w;
        __syncthreads();                 // LDS[buf] ready (single barrier per slab)

        // issue next slab's global loads (overlap with compute below)
        if (bk + 16 < KA) {
            const int k0 = bk + 16 + kq;
            if (mode == 0) {
                const float* p = A + (size_t)(bm + lrow) * KA + k0;
                a0 = *(const float4*)p; a1 = *(const float4*)(p + 4);
            } else {
                const int arow = bm + lrow;
                const float* p0 = (k0 < 512) ? (hf + (size_t)(arow + 1) * HID + k0)
                                             : (hb + (size_t)(SEQ - arow) * HID + (k0 - 512));
                const int k1 = k0 + 4;
                const float* p1 = (k1 < 512) ? (hf + (size_t)(arow + 1) * HID + k1)
                                             : (hb + (size_t)(SEQ - arow) * HID + (k1 - 512));
                a0 = *(const float4*)p0; a1 = *(const float4*)p1;
            }
            const float* qp = W + (size_t)(bn + lrow) * KA + k0;
            w0 = *(const float4*)qp; w1 = *(const float4*)(qp + 4);
        }

        #pragma unroll
        for (int kk = 0; kk < 16; ++kk) {
            const float4 av0 = *(const float4*)&As[buf][kk][ty * 8];
            const float4 av1 = *(const float4*)&As[buf][kk][ty * 8 + 4];
            const float4 bv0 = *(const float4*)&Ws[buf][kk][bpos];
            const float4 bv1 = *(const float4*)&Ws[buf][kk][bpos + 4];
            const float a8[8] = {av0.x, av0.y, av0.z, av0.w, av1.x, av1.y, av1.z, av1.w};
            const float b8[8] = {bv0.x, bv0.y, bv0.z, bv0.w, bv1.x, bv1.y, bv1.z, bv1.w};
            #pragma unroll
            for (int i = 0; i < 8; ++i)
                #pragma unroll
                for (int j = 0; j < 8; ++j)
                    acc[i][j] = fmaf(a8[i], b8[j], acc[i][j]);
        }
        buf ^= 1;
        // no second barrier: fast threads write the OTHER buffer next slab;
        // reads of that buffer finished before the barrier all threads passed.
    }

    const float4 bx0 = *(const float4*)&bias[bn + tx * 8];
    const float4 bx1 = *(const float4*)&bias[bn + tx * 8 + 4];
    #pragma unroll
    for (int im = 0; im < 8; ++im) {
        float4 o0, o1;
        o0.x = acc[im][0] + bx0.x; o0.y = acc[im][1] + bx0.y;
        o0.z = acc[im][2] + bx0.z; o0.w = acc[im][3] + bx0.w;
        o1.x = acc[im][4] + bx1.x; o1.y = acc[im][5] + bx1.y;
        o1.z = acc[im][6] + bx1.z; o1.w = acc[im][7] + bx1.w;
        float* cp = &C[(size_t)(bm + ty * 8 + im) * G4H + bn + tx * 8];
        *(float4*)cp = o0;
        *(float4*)(cp + 4) = o1;
    }
}

// =====================================================================
// Persistent bidirectional LSTM layer, v10: Whh staged in LDS.
// Model revision (v9 post-mortem): VGPR=56 across ALL variants means the
// 64 weight floats/thread re-load from L2 inside the matvec EVERY STEP:
// 128 KB/WG/step of L2->CU traffic at ~50-60 B/cy/CU = ~2300cy — over
// half the ~4330cy period. Serial-chain shaves (v3/v6/v9, <=80cy each)
// were hiding in this streaming phase's shadow; register-residency
// attempts (v5 spill, v8b ignored) failed at the compiler.
// Fix: the WG's 64x512 weight slice (128 KB) FITS IN LDS (160 KB).
// Preamble loads it once; the matvec streams weights from LDS at
// ~128 B/cy (~1024cy) with zero LLC contention. Layout
// row*521 + chunk*65 + j (odd strides): bank = (9*rr+q+j) mod 32 ->
// 2-way conflicts (free, m136); odd offsets also stop the compiler from
// merging scalar reads into 8-way-conflicting ds_read_b128.
// The FMA chain is the SAME 64 fmafs in the SAME ascending order on the
// SAME values -> bit-exact (absmax must stay 0.0).
// Everything else = v9: part[]-scatter/wave0-gather reduce, v6 tight
// poll, zP pipelined one step ahead, single 64B hist store.
// =====================================================================
constexpr int WROW = 521;   // padded weight row stride (words)
constexpr int WCH  = 65;    // padded chunk stride within a row (words)

__global__ __launch_bounds__(512, 2) void lstm_layer(
    const float* __restrict__ Pf, const float* __restrict__ Pb,
    const float* __restrict__ Whhf, const float* __restrict__ Whhb,
    const float* __restrict__ h0, const float* __restrict__ c0, int h0base,
    float* __restrict__ histf, float* __restrict__ histb)
{
    const int wg  = blockIdx.x;
    const int dir = wg >> 5;            // 0 fwd, 1 bwd (32 WGs each)
    const int w   = wg & 31;            // slice id: units [w*16, w*16+16)
    const float* P    = dir ? Pb : Pf;
    const float* Whh  = dir ? Whhb : Whhf;
    float* histW      = dir ? histb : histf;

    const int tid  = threadIdx.x;              // 0..511
    const int wave = tid >> 6;                 // 0..7
    const int lane = tid & 63;
    const int q    = lane >> 3;                // k-chunk 0..7
    const int rr   = lane & 7;                 // row-in-wave 0..7
    const int g    = wave >> 1;                // gate 0..3 (i,f,g,o)
    const int usub = (wave & 1) * 8;
    const int uu   = usub + rr;                // unit-in-WG 0..15 (this row)
    const int unit = w * 16 + uu;              // global unit [0,512)
    const int grow = g * HID + unit;           // matvec-role z-row [0,2048)
    const int prow = g * 16 + uu;              // part[]/weight row index 0..63

    // reduce-role indices (wave 0 only): lane r handles part row r
    const int gR    = lane >> 4;               // gate of reduced row
    const int uR    = lane & 15;               // unit of reduced row
    const int growR = gR * HID + w * 16 + uR;  // z-row for zP prefetch

    // ---- LDS: weights (130.3 KB) + padded h + part[] ----
    __shared__ __align__(16) float hsp[8 * 68];       // h, chunk k at [k*68, k*68+64)
    __shared__ float part[64][9];                     // raw chunk partials
    __shared__ float wlds[64 * WROW];                 // weight slice, padded

    // preamble: stage this WG's 64x512 weight slice into LDS (one-time)
    {
        const float4* wp = (const float4*)(Whh + (size_t)grow * HID + q * 64);
        float* wb = &wlds[prow * WROW + q * WCH];
        #pragma unroll
        for (int i = 0; i < 16; ++i) {
            const float4 v = wp[i];
            wb[4*i+0] = v.x; wb[4*i+1] = v.y; wb[4*i+2] = v.z; wb[4*i+3] = v.w;
        }
    }

    // cell state on the first 16 threads (one per unit)
    float c = 0.0f;
    if (tid < 16) c = c0[(size_t)(h0base + dir) * HID + w * 16 + tid];

    // initial h into padded LDS
    hsp[(tid >> 6) * 68 + (tid & 63)] = h0[(size_t)(h0base + dir) * HID + tid];
    __syncthreads();                               // weights + h staged

    // zP for step 0; thereafter software-pipelined one step ahead.
    // Wave 0 holds zP for ALL 64 rows (lane r -> row r's term).
    float zPc = 0.0f;
    if (wave == 0) zPc = P[(size_t)(dir ? (SEQ - 1) : 0) * G4H + growR];

    for (int s = 0; s < SEQ; ++s) {
        // prefetch NEXT step's input-projection term (off critical path)
        float zPn = 0.0f;
        if (wave == 0 && s + 1 < SEQ) {
            const int tn = dir ? (SEQ - 2 - s) : (s + 1);
            zPn = P[(size_t)tn * G4H + growR];
        }

        // matvec partial: SAME ordered 64-fma chain, weights now from LDS.
        float acc = 0.0f;
        {
            const float* hb4 = &hsp[q * 68];
            const float* wb  = &wlds[prow * WROW + q * WCH];
            #pragma unroll
            for (int i = 0; i < 16; ++i) {
                const float4 h4 = *(const float4*)&hb4[4*i];
                acc = fmaf(wb[4*i+0], h4.x, acc);
                acc = fmaf(wb[4*i+1], h4.y, acc);
                acc = fmaf(wb[4*i+2], h4.z, acc);
                acc = fmaf(wb[4*i+3], h4.w, acc);
            }
        }

        // scatter raw partial (ONE ds_write pre-barrier)
        part[prow][q] = acc;
        __syncthreads();                           // B1: part[] complete

        if (wave == 0) {
            // lane r reduces row r: 8 conflict-free scalar LDS reads
            float p0 = part[lane][0], p1 = part[lane][1];
            float p2 = part[lane][2], p3 = part[lane][3];
            float p4 = part[lane][4], p5 = part[lane][5];
            float p6 = part[lane][6], p7 = part[lane][7];
            // EXACT v1 association: s2_i = c_{2i}+c_{2i+1};
            // z = ((s2_0+s2_1)+s2_2)+s2_3 + zP
            const float s20 = p0 + p1, s21 = p2 + p3;
            const float s22 = p4 + p5, s23 = p6 + p7;
            float z = s20 + s21;
            z += s22;
            z += s23;
            z += zPc;
            // activation (identical functions on identical inputs)
            const float act = (gR == 2) ? tanhf(z) : sigm(z);
            // gather the 4 gates of unit uR
            const float ai = __shfl(act, uR);
            const float af = __shfl(act, 16 + uR);
            const float ag = __shfl(act, 32 + uR);
            const float ao = __shfl(act, 48 + uR);
            if (lane < 16) {
                const float cn = af * c + ai * ag;  // == sigm(zf)*c + sigm(zi)*tanhf(zg)
                const float hv = ao * tanhf(cn);    // == sigm(zo)*tanhf(cn)
                c = cn;
                // 16 lanes x 4B contiguous, 64B-aligned = one write transaction
                __hip_atomic_store(&histW[(size_t)(s + 1) * HID + w * 16 + lane], hv,
                                   __ATOMIC_RELAXED, __HIP_MEMORY_SCOPE_AGENT);
            }
        }
        zPc = zPn;

        if (s + 1 < SEQ) {
            // v6 tight poll (PROVEN): one load outstanding per thread.
            const uint32_t* src = (const uint32_t*)(histW + (size_t)(s + 1) * HID);
            uint32_t A = __hip_atomic_load(&src[tid], __ATOMIC_RELAXED, __HIP_MEMORY_SCOPE_AGENT);
            uint32_t B = __hip_atomic_load(&src[tid], __ATOMIC_RELAXED, __HIP_MEMORY_SCOPE_AGENT);
            while (A == 0xFFFFFFFFu) {
                A = B;
                B = __hip_atomic_load(&src[tid], __ATOMIC_RELAXED, __HIP_MEMORY_SCOPE_AGENT);
            }
            hsp[(tid >> 6) * 68 + (tid & 63)] = __uint_as_float(A);
            __syncthreads();                       // B2: hs[s+1] complete,
                                                   // also fences part[] reuse
        }
    }
}

// =====================================================================
// feats[t][j] = b_tag[j] + sum_k y1[t][k] * Wtag[j][k], y1 from hist buffers.
// One wave per t-row.
// =====================================================================
__global__ __launch_bounds__(256) void feats_kernel(
    const float* __restrict__ hf, const float* __restrict__ hb,
    const float* __restrict__ Wtag, const float* __restrict__ btag, float* __restrict__ feats)
{
    const int wv = threadIdx.x >> 6, lane = threadIdx.x & 63;
    const int t  = blockIdx.x * 4 + wv;
    const int k0 = lane * 16;
    const float* src = (k0 < 512) ? (hf + (size_t)(t + 1) * HID + k0)
                                  : (hb + (size_t)(SEQ - t) * HID + (k0 - 512));
    const float4 y0 = ((const float4*)src)[0];
    const float4 y1 = ((const float4*)src)[1];
    const float4 y2 = ((const float4*)src)[2];
    const float4 y3 = ((const float4*)src)[3];
    for (int j = 0; j < KTAG; ++j) {
        const float4* wp = (const float4*)&Wtag[(size_t)j * 1024 + k0];
        const float4 w0 = wp[0], w1 = wp[1], w2 = wp[2], w3 = wp[3];
        float p = 0.0f;
        p = fmaf(y0.x, w0.x, p); p = fmaf(y0.y, w0.y, p); p = fmaf(y0.z, w0.z, p); p = fmaf(y0.w, w0.w, p);
        p = fmaf(y1.x, w1.x, p); p = fmaf(y1.y, w1.y, p); p = fmaf(y1.z, w1.z, p); p = fmaf(y1.w, w1.w, p);
        p = fmaf(y2.x, w2.x, p); p = fmaf(y2.y, w2.y, p); p = fmaf(y2.z, w2.z, p); p = fmaf(y2.w, w2.w, p);
        p = fmaf(y3.x, w3.x, p); p = fmaf(y3.y, w3.y, p); p = fmaf(y3.z, w3.z, p); p = fmaf(y3.w, w3.w, p);
        #pragma unroll
        for (int off = 32; off; off >>= 1) p += __shfl_xor(p, off);
        if (lane == 0) feats[(size_t)t * KTAG + j] = p + btag[j];
    }
}

// =====================================================================
// Sequential Viterbi max scan (bit-exact vs reference, no argmax on chain).
// 1 wave. Lane layout: to = lane%24, half = lane/24 covers 12 'from' each.
// fv rows stored to fvstore (slot 0 = init, slot t+1 = fv_t) for bp recompute.
// =====================================================================
__global__ __launch_bounds__(64) void viterbi_scan(
    const float* __restrict__ feats, const float* __restrict__ trans,
    float* __restrict__ fvstore, float* __restrict__ out, int* __restrict__ bestb)
{
    const int lane = threadIdx.x;
    const int to = lane % 24, hh = lane / 24;
    const bool act = hh < 2;
    const int hb = (hh & 1) * 12;

    float tr[12], fvr[12];
    #pragma unroll
    for (int i = 0; i < 12; ++i) tr[i] = act ? trans[to * 24 + hb + i] : -3.0e37f;
    #pragma unroll
    for (int i = 0; i < 12; ++i) fvr[i] = (hb + i == 0) ? 0.0f : NEGV;
    if (lane < 24) fvstore[lane] = (lane == 0) ? 0.0f : NEGV;

    float ftc = (lane < 24) ? feats[lane] : 0.0f;
    const int partner = act ? (to + ((hh ^ 1) * 24)) : lane;
    float fvnew = 0.0f;

    for (int t = 0; t < SEQ; ++t) {
        const float ftn = (lane < 24 && t + 1 < SEQ) ? feats[(size_t)(t + 1) * KTAG + lane] : 0.0f;
        float v0  = fvr[0]  + tr[0],  v1  = fvr[1]  + tr[1];
        float v2  = fvr[2]  + tr[2],  v3  = fvr[3]  + tr[3];
        float v4  = fvr[4]  + tr[4],  v5  = fvr[5]  + tr[5];
        float v6  = fvr[6]  + tr[6],  v7  = fvr[7]  + tr[7];
        float v8  = fvr[8]  + tr[8],  v9  = fvr[9]  + tr[9];
        float v10 = fvr[10] + tr[10], v11 = fvr[11] + tr[11];
        float m = fmaxf(fmaxf(fmaxf(v0, v1), fmaxf(v2, v3)),
                        fmaxf(fmaxf(v4, v5), fmaxf(v6, v7)));
        m = fmaxf(m, fmaxf(fmaxf(v8, v9), fmaxf(v10, v11)));
        m = fmaxf(m, __shfl(m, partner));
        fvnew = m + ftc;                 // valid on lanes < 24
        if (lane < 24) fvstore[(size_t)(t + 1) * KTAG + lane] = fvnew;
        #pragma unroll
        for (int i = 0; i < 12; ++i) fvr[i] = __shfl(fvnew, hb + i);   // re-replicate
        ftc = ftn;
    }

    // terminal
    float val = -3.0e38f; int idx = lane;
    if (lane < 24) {
        val = fvnew + trans[1 * 24 + lane];          // transitions[STOP][from]
        if (lane == 0 || lane == 1) val = NEGV;      // exclude START, STOP
    }
    #pragma unroll
    for (int off = 16; off; off >>= 1) {
        const float ov = __shfl_xor(val, off);
        const int   oi = __shfl_xor(idx, off);
        if (ov > val || (ov == val && oi < idx)) { val = ov; idx = oi; }
    }
    if (lane == 0) { out[0] = val; *bestb = idx; }
}

// =====================================================================
// Recompute backpointers in parallel: bp[t][to] = argmax_from(fv_{t-1}[from]+trans)
// Identical fp32 adds + first-index tie rule -> matches the sequential scan.
// =====================================================================
__global__ __launch_bounds__(256) void bp_kernel(
    const float* __restrict__ fvstore, const float* __restrict__ trans, uint8_t* __restrict__ bp)
{
    const int idx = blockIdx.x * 256 + threadIdx.x;
    const int t = idx / KTAG, to = idx % KTAG;
    const float* fv = fvstore + (size_t)t * KTAG;   // slot t = fv_{t-1}
    const float* tr = trans + to * 24;
    float m = fv[0] + tr[0]; int bi = 0;
    #pragma unroll
    for (int f = 1; f < 24; ++f) {
        const float v = fv[f] + tr[f];
        if (v > m) { m = v; bi = f; }
    }
    bp[idx] = (uint8_t)bi;
}

// =====================================================================
// Parallel backtrace via exact integer map composition over 64-step chunks.
// =====================================================================
__global__ __launch_bounds__(1024) void backtrace_kernel(
    const uint8_t* __restrict__ bp, const int* __restrict__ bestb, float* __restrict__ out)
{
    __shared__ uint8_t E[64][24];
    __shared__ uint8_t tops[64];
    const int tid = threadIdx.x;
    const int wv = tid >> 6, lane = tid & 63;

    // phase 1: chunk maps E_c: top_c -> top_{c-1} (applies bp[64c+63] .. bp[64c])
    for (int ci = 0; ci < 4; ++ci) {
        const int ck = wv * 4 + ci;
        if (lane < 24) {
            int y = lane;
            for (int k = 63; k >= 0; --k) y = bp[(size_t)(ck * 64 + k) * KTAG + y];
            E[ck][lane] = (uint8_t)y;
        }
    }
    __syncthreads();

    // phase 2: serial fold over 64 chunk maps
    if (tid == 0) {
        int topc = *bestb;
        tops[63] = (uint8_t)topc;
        for (int ck = 63; ck >= 1; --ck) { topc = E[ck][topc]; tops[ck - 1] = (uint8_t)topc; }
    }
    __syncthreads();

    // phase 3: fill each chunk
    for (int ci = 0; ci < 4; ++ci) {
        const int ck = wv * 4 + ci;
        if (lane == 0) {
            int y = tops[ck];
            out[1 + ck * 64 + 63] = (float)y;
            for (int tt = ck * 64 + 62; tt >= ck * 64; --tt) {
                y = bp[(size_t)(tt + 1) * KTAG + y];
                out[1 + tt] = (float)y;
            }
        }
    }
}

// =====================================================================
extern "C" void kernel_launch(void* const* d_in, const int* in_sizes, int n_in,
                              void* d_out, int out_size, void* d_ws, size_t ws_size,
                              hipStream_t stream)
{
    (void)in_sizes; (void)n_in; (void)out_size; (void)ws_size;
    // Inputs in setup_inputs() dict INSERTION order: transitions is added
    // LAST (after h0/c0), even though the reference signature lists it earlier.
    const float* X     = (const float*)d_in[0];
    const float* Wih0f = (const float*)d_in[1];
    const float* Whh0f = (const float*)d_in[2];
    const float* b0f   = (const float*)d_in[3];
    const float* Wih0b = (const float*)d_in[4];
    const float* Whh0b = (const float*)d_in[5];
    const float* b0b   = (const float*)d_in[6];
    const float* Wih1f = (const float*)d_in[7];
    const float* Whh1f = (const float*)d_in[8];
    const float* b1f   = (const float*)d_in[9];
    const float* Wih1b = (const float*)d_in[10];
    const float* Whh1b = (const float*)d_in[11];
    const float* b1b   = (const float*)d_in[12];
    const float* Wtag  = (const float*)d_in[13];
    const float* btag  = (const float*)d_in[14];
    const float* h0    = (const float*)d_in[15];
    const float* c0    = (const float*)d_in[16];
    const float* trans = (const float*)d_in[17];
    float* out = (float*)d_out;

    // workspace carve-up (floats)
    float* f   = (float*)d_ws;
    float* Pf  = f;                                   // SEQ*2048
    float* Pb  = Pf  + (size_t)SEQ * G4H;             // SEQ*2048
    float* hf0 = Pb  + (size_t)SEQ * G4H;             // (SEQ+1)*512 each
    float* hb0 = hf0 + (size_t)(SEQ + 1) * HID;
    float* hf1 = hb0 + (size_t)(SEQ + 1) * HID;
    float* hb1 = hf1 + (size_t)(SEQ + 1) * HID;
    float* feats = hb1 + (size_t)(SEQ + 1) * HID;     // SEQ*24
    float* fvst  = feats + (size_t)SEQ * KTAG;        // (SEQ+1)*24
    int*   bestb = (int*)(fvst + (size_t)(SEQ + 1) * KTAG);
    uint8_t* bp  = (uint8_t*)(bestb + 4);             // SEQ*24 bytes

    // NaN-sentinel fill for all 4 hist buffers (sync mechanism for the LSTM)
    hipMemsetAsync(hf0, 0xFF, (size_t)4 * (SEQ + 1) * HID * sizeof(float), stream);

    // layer 0: input projection, then persistent bidirectional recurrence
    gemm_proj<<<dim3(SEQ / 128, G4H / 128, 2), 256, 0, stream>>>(
        X, nullptr, nullptr, DIN, 0, Wih0f, b0f, Pf, Wih0b, b0b, Pb);
    lstm_layer<<<64, 512, 0, stream>>>(Pf, Pb, Whh0f, Whh0b, h0, c0, 0, hf0, hb0);

    // layer 1 (P buffers reused; layer-0 input y0 read straight from hist)
    gemm_proj<<<dim3(SEQ / 128, G4H / 128, 2), 256, 0, stream>>>(
        nullptr, hf0, hb0, 1024, 1, Wih1f, b1f, Pf, Wih1b, b1b, Pb);
    lstm_layer<<<64, 512, 0, stream>>>(Pf, Pb, Whh1f, Whh1b, h0, c0, 2, hf1, hb1);

    // tag head + Viterbi
    feats_kernel<<<SEQ / 4, 256, 0, stream>>>(hf1, hb1, Wtag, btag, feats);
    viterbi_scan<<<1, 64, 0, stream>>>(feats, trans, fvst, out, bestb);
    bp_kernel<<<(SEQ * KTAG) / 256, 256, 0, stream>>>(fvst, trans, bp);
    backtrace_kernel<<<1, 1024, 0, stream>>>(bp, bestb, out);
}

// Round 12
// 17732.162 us; speedup vs baseline: 1.2912x; 1.2912x over previous
//
#include <hip/hip_runtime.h>
#include <hip/hip_bf16.h>
#include <stdint.h>
#include <math.h>

// Problem dims
constexpr int SEQ  = 4096;
constexpr int DIN  = 1152;
constexpr int HID  = 512;
constexpr int G4H  = 2048;   // 4*HID
constexpr int KTAG = 24;
constexpr float NEGV = -10000.0f;

__device__ __forceinline__ float sigm(float x) { return 1.0f / (1.0f + expf(-x)); }

// =====================================================================
// GEMM: C[SEQ][2048] = A[SEQ][KA] @ W[2048][KA]^T + b   (fp32, 128x128 tile,
// 8x8 per thread, K-step 16, DOUBLE-BUFFERED LDS: one barrier per K-slab,
// global loads for slab k+1 issued under compute of slab k).
// Per-element accumulation is a single fmaf chain in strictly ascending k
// with bias added last -> BIT-EXACT with the original tiling (absmax 0.0).
// =====================================================================
__global__ __launch_bounds__(256) void gemm_proj(
    const float* __restrict__ A, const float* __restrict__ hf, const float* __restrict__ hb,
    int KA, int mode,
    const float* __restrict__ Wf, const float* __restrict__ bf, float* __restrict__ Cf,
    const float* __restrict__ Wb, const float* __restrict__ bb, float* __restrict__ Cb)
{
    const float* W    = blockIdx.z ? Wb : Wf;
    const float* bias = blockIdx.z ? bb : bf;
    float*       C    = blockIdx.z ? Cb : Cf;

    __shared__ __align__(16) float As[2][16][132];   // [buf][k][m], pad 132
    __shared__ __align__(16) float Ws[2][16][144];   // [buf][k][pos(n)], bank-spread

    const int tid  = threadIdx.x;
    const int bm   = blockIdx.x * 128;
    const int bn   = blockIdx.y * 128;
    const int lrow = tid >> 1;            // 0..127
    const int kq   = (tid & 1) * 8;       // 0 or 8
    const int tx   = tid & 15;            // col block (8 wide)
    const int ty   = tid >> 4;            // row block (8 tall)
    const int wpos = lrow + 4 * (lrow >> 5);        // Ws write position
    const int bpos = tx * 8 + 4 * (tx >> 2);        // Ws read position

    float acc[8][8] = {};
    float4 a0, a1, w0, w1;

    // load slab 0 into registers
    {
        const int k0 = kq;
        if (mode == 0) {
            const float* p = A + (size_t)(bm + lrow) * KA + k0;
            a0 = *(const float4*)p; a1 = *(const float4*)(p + 4);
        } else {
            const int arow = bm + lrow;
            const float* p0 = (k0 < 512) ? (hf + (size_t)(arow + 1) * HID + k0)
                                         : (hb + (size_t)(SEQ - arow) * HID + (k0 - 512));
            const int k1 = k0 + 4;
            const float* p1 = (k1 < 512) ? (hf + (size_t)(arow + 1) * HID + k1)
                                         : (hb + (size_t)(SEQ - arow) * HID + (k1 - 512));
            a0 = *(const float4*)p0; a1 = *(const float4*)p1;
        }
        const float* qp = W + (size_t)(bn + lrow) * KA + k0;
        w0 = *(const float4*)qp; w1 = *(const float4*)(qp + 4);
    }

    int buf = 0;
    for (int bk = 0; bk < KA; bk += 16) {
        // stage current slab regs -> LDS[buf]
        As[buf][kq+0][lrow] = a0.x; As[buf][kq+1][lrow] = a0.y; As[buf][kq+2][lrow] = a0.z; As[buf][kq+3][lrow] = a0.w;
        As[buf][kq+4][lrow] = a1.x; As[buf][kq+5][lrow] = a1.y; As[buf][kq+6][lrow] = a1.z; As[buf][kq+7][lrow] = a1.w;
        Ws[buf][kq+0][wpos] = w0.x; Ws[buf][kq+1][wpos] = w0.y; Ws[buf][kq+2][wpos] = w0.z; Ws[buf][kq+3][wpos] = w0.w;
        Ws[buf][kq+4][wpos] = w1.x; Ws[buf][kq+5][wpos] = w1.y; Ws[buf][kq+6][wpos] = w1.z; Ws[buf][kq+7][wpos] = w1.w;
        __syncthreads();                 // LDS[buf] ready (single barrier per slab)

        // issue next slab's global loads (overlap with compute below)
        if (bk + 16 < KA) {
            const int k0 = bk + 16 + kq;
            if (mode == 0) {
                const float* p = A + (size_t)(bm + lrow) * KA + k0;
                a0 = *(const float4*)p; a1 = *(const float4*)(p + 4);
            } else {
                const int arow = bm + lrow;
                const float* p0 = (k0 < 512) ? (hf + (size_t)(arow + 1) * HID + k0)
                                             : (hb + (size_t)(SEQ - arow) * HID + (k0 - 512));
                const int k1 = k0 + 4;
                const float* p1 = (k1 < 512) ? (hf + (size_t)(arow + 1) * HID + k1)
                                             : (hb + (size_t)(SEQ - arow) * HID + (k1 - 512));
                a0 = *(const float4*)p0; a1 = *(const float4*)p1;
            }
            const float* qp = W + (size_t)(bn + lrow) * KA + k0;
            w0 = *(const float4*)qp; w1 = *(const float4*)(qp + 4);
        }

        #pragma unroll
        for (int kk = 0; kk < 16; ++kk) {
            const float4 av0 = *(const float4*)&As[buf][kk][ty * 8];
            const float4 av1 = *(const float4*)&As[buf][kk][ty * 8 + 4];
            const float4 bv0 = *(const float4*)&Ws[buf][kk][bpos];
            const float4 bv1 = *(const float4*)&Ws[buf][kk][bpos + 4];
            const float a8[8] = {av0.x, av0.y, av0.z, av0.w, av1.x, av1.y, av1.z, av1.w};
            const float b8[8] = {bv0.x, bv0.y, bv0.z, bv0.w, bv1.x, bv1.y, bv1.z, bv1.w};
            #pragma unroll
            for (int i = 0; i < 8; ++i)
                #pragma unroll
                for (int j = 0; j < 8; ++j)
                    acc[i][j] = fmaf(a8[i], b8[j], acc[i][j]);
        }
        buf ^= 1;
        // no second barrier: fast threads write the OTHER buffer next slab;
        // reads of that buffer finished before the barrier all threads passed.
    }

    const float4 bx0 = *(const float4*)&bias[bn + tx * 8];
    const float4 bx1 = *(const float4*)&bias[bn + tx * 8 + 4];
    #pragma unroll
    for (int im = 0; im < 8; ++im) {
        float4 o0, o1;
        o0.x = acc[im][0] + bx0.x; o0.y = acc[im][1] + bx0.y;
        o0.z = acc[im][2] + bx0.z; o0.w = acc[im][3] + bx0.w;
        o1.x = acc[im][4] + bx1.x; o1.y = acc[im][5] + bx1.y;
        o1.z = acc[im][6] + bx1.z; o1.w = acc[im][7] + bx1.w;
        float* cp = &C[(size_t)(bm + ty * 8 + im) * G4H + bn + tx * 8];
        *(float4*)cp = o0;
        *(float4*)(cp + 4) = o1;
    }
}

// =====================================================================
// Persistent bidirectional LSTM layer, v11: Whh in LDS, VECTORIZED +
// LINEAR-PER-WAVE (v10 post-mortem fix).
// v10 failed on its LAYOUT, not the hypothesis: odd strides forced 64
// scalar ds_read_b32/thread and a skewed (1-to-3-way) bank map ->
// SQ_LDS_BANK_CONFLICT 2.7e8, +1040cy/WG/step. v11 stores weight float4
// #i of thread (wave,lane) at wlds4[wave*SLAB + i*64 + lane]: per wave
// and per i, the 64 lanes read 64 CONTIGUOUS 16B slots (bank group =
// lane mod 8, uniform) — the canonical conflict-free linear b128
// pattern (same family as hsp's measured-0-conflict reads). Staging
// writes are linear too. 16 ds_read_b128 (weights) + 16 (h) per thread
// per step; weight traffic moves off L2 entirely (frees the LLC path
// the sync depends on).
// FMA chain: SAME 64 fmafs, SAME ascending order, SAME values ->
// bit-exact (absmax must stay 0.0).
// Everything else = v9: part[]-scatter/wave0-gather reduce, v6 tight
// poll, zP pipelined one step ahead, single 64B hist store.
// =====================================================================
constexpr int SLAB = 16 * 64 + 8;   // float4 units per wave-slab (pad 8)

__global__ __launch_bounds__(512, 2) void lstm_layer(
    const float* __restrict__ Pf, const float* __restrict__ Pb,
    const float* __restrict__ Whhf, const float* __restrict__ Whhb,
    const float* __restrict__ h0, const float* __restrict__ c0, int h0base,
    float* __restrict__ histf, float* __restrict__ histb)
{
    const int wg  = blockIdx.x;
    const int dir = wg >> 5;            // 0 fwd, 1 bwd (32 WGs each)
    const int w   = wg & 31;            // slice id: units [w*16, w*16+16)
    const float* P    = dir ? Pb : Pf;
    const float* Whh  = dir ? Whhb : Whhf;
    float* histW      = dir ? histb : histf;

    const int tid  = threadIdx.x;              // 0..511
    const int wave = tid >> 6;                 // 0..7
    const int lane = tid & 63;
    const int q    = lane >> 3;                // k-chunk 0..7
    const int rr   = lane & 7;                 // row-in-wave 0..7
    const int g    = wave >> 1;                // gate 0..3 (i,f,g,o)
    const int usub = (wave & 1) * 8;
    const int uu   = usub + rr;                // unit-in-WG 0..15 (this row)
    const int unit = w * 16 + uu;              // global unit [0,512)
    const int grow = g * HID + unit;           // matvec-role z-row [0,2048)
    const int prow = g * 16 + uu;              // part[] row index 0..63
                                               // note: prow>>3 == wave, prow&7 == rr

    // reduce-role indices (wave 0 only): lane r handles part row r
    const int gR    = lane >> 4;               // gate of reduced row
    const int uR    = lane & 15;               // unit of reduced row
    const int growR = gR * HID + w * 16 + uR;  // z-row for zP prefetch

    // ---- LDS: weights (132 KB, vectorized) + padded h + part[] ----
    __shared__ __align__(16) float hsp[8 * 68];       // h, chunk k at [k*68, k*68+64)
    __shared__ float part[64][9];                     // raw chunk partials
    __shared__ __align__(16) float4 wlds4[8 * SLAB];  // weight slice

    // preamble: stage this WG's 64x512 weight slice into LDS (one-time).
    // Thread (wave,lane) owns float4s {wlds4[wave*SLAB + i*64 + lane]}.
    {
        const float4* wp = (const float4*)(Whh + (size_t)grow * HID + q * 64);
        float4* wb = &wlds4[wave * SLAB + lane];
        #pragma unroll
        for (int i = 0; i < 16; ++i) wb[i * 64] = wp[i];
    }

    // cell state on the first 16 threads (one per unit)
    float c = 0.0f;
    if (tid < 16) c = c0[(size_t)(h0base + dir) * HID + w * 16 + tid];

    // initial h into padded LDS
    hsp[(tid >> 6) * 68 + (tid & 63)] = h0[(size_t)(h0base + dir) * HID + tid];
    __syncthreads();                               // weights + h staged

    // zP for step 0; thereafter software-pipelined one step ahead.
    // Wave 0 holds zP for ALL 64 rows (lane r -> row r's term).
    float zPc = 0.0f;
    if (wave == 0) zPc = P[(size_t)(dir ? (SEQ - 1) : 0) * G4H + growR];

    for (int s = 0; s < SEQ; ++s) {
        // prefetch NEXT step's input-projection term (off critical path)
        float zPn = 0.0f;
        if (wave == 0 && s + 1 < SEQ) {
            const int tn = dir ? (SEQ - 2 - s) : (s + 1);
            zPn = P[(size_t)tn * G4H + growR];
        }

        // matvec partial: SAME ordered 64-fma chain; weights via linear
        // conflict-free ds_read_b128 from LDS.
        float acc = 0.0f;
        {
            const float* hb4 = &hsp[q * 68];
            const float4* wb = &wlds4[wave * SLAB + lane];
            #pragma unroll
            for (int i = 0; i < 16; ++i) {
                const float4 h4 = *(const float4*)&hb4[4 * i];
                const float4 wv = wb[i * 64];
                acc = fmaf(wv.x, h4.x, acc);
                acc = fmaf(wv.y, h4.y, acc);
                acc = fmaf(wv.z, h4.z, acc);
                acc = fmaf(wv.w, h4.w, acc);
            }
        }

        // scatter raw partial (ONE ds_write pre-barrier)
        part[prow][q] = acc;
        __syncthreads();                           // B1: part[] complete

        if (wave == 0) {
            // lane r reduces row r: 8 conflict-free scalar LDS reads
            float p0 = part[lane][0], p1 = part[lane][1];
            float p2 = part[lane][2], p3 = part[lane][3];
            float p4 = part[lane][4], p5 = part[lane][5];
            float p6 = part[lane][6], p7 = part[lane][7];
            // EXACT v1 association: s2_i = c_{2i}+c_{2i+1};
            // z = ((s2_0+s2_1)+s2_2)+s2_3 + zP
            const float s20 = p0 + p1, s21 = p2 + p3;
            const float s22 = p4 + p5, s23 = p6 + p7;
            float z = s20 + s21;
            z += s22;
            z += s23;
            z += zPc;
            // activation (identical functions on identical inputs)
            const float act = (gR == 2) ? tanhf(z) : sigm(z);
            // gather the 4 gates of unit uR
            const float ai = __shfl(act, uR);
            const float af = __shfl(act, 16 + uR);
            const float ag = __shfl(act, 32 + uR);
            const float ao = __shfl(act, 48 + uR);
            if (lane < 16) {
                const float cn = af * c + ai * ag;  // == sigm(zf)*c + sigm(zi)*tanhf(zg)
                const float hv = ao * tanhf(cn);    // == sigm(zo)*tanhf(cn)
                c = cn;
                // 16 lanes x 4B contiguous, 64B-aligned = one write transaction
                __hip_atomic_store(&histW[(size_t)(s + 1) * HID + w * 16 + lane], hv,
                                   __ATOMIC_RELAXED, __HIP_MEMORY_SCOPE_AGENT);
            }
        }
        zPc = zPn;

        if (s + 1 < SEQ) {
            // v6 tight poll (PROVEN): one load outstanding per thread.
            const uint32_t* src = (const uint32_t*)(histW + (size_t)(s + 1) * HID);
            uint32_t A = __hip_atomic_load(&src[tid], __ATOMIC_RELAXED, __HIP_MEMORY_SCOPE_AGENT);
            uint32_t B = __hip_atomic_load(&src[tid], __ATOMIC_RELAXED, __HIP_MEMORY_SCOPE_AGENT);
            while (A == 0xFFFFFFFFu) {
                A = B;
                B = __hip_atomic_load(&src[tid], __ATOMIC_RELAXED, __HIP_MEMORY_SCOPE_AGENT);
            }
            hsp[(tid >> 6) * 68 + (tid & 63)] = __uint_as_float(A);
            __syncthreads();                       // B2: hs[s+1] complete,
                                                   // also fences part[] reuse
        }
    }
}

// =====================================================================
// feats[t][j] = b_tag[j] + sum_k y1[t][k] * Wtag[j][k], y1 from hist buffers.
// One wave per t-row.
// =====================================================================
__global__ __launch_bounds__(256) void feats_kernel(
    const float* __restrict__ hf, const float* __restrict__ hb,
    const float* __restrict__ Wtag, const float* __restrict__ btag, float* __restrict__ feats)
{
    const int wv = threadIdx.x >> 6, lane = threadIdx.x & 63;
    const int t  = blockIdx.x * 4 + wv;
    const int k0 = lane * 16;
    const float* src = (k0 < 512) ? (hf + (size_t)(t + 1) * HID + k0)
                                  : (hb + (size_t)(SEQ - t) * HID + (k0 - 512));
    const float4 y0 = ((const float4*)src)[0];
    const float4 y1 = ((const float4*)src)[1];
    const float4 y2 = ((const float4*)src)[2];
    const float4 y3 = ((const float4*)src)[3];
    for (int j = 0; j < KTAG; ++j) {
        const float4* wp = (const float4*)&Wtag[(size_t)j * 1024 + k0];
        const float4 w0 = wp[0], w1 = wp[1], w2 = wp[2], w3 = wp[3];
        float p = 0.0f;
        p = fmaf(y0.x, w0.x, p); p = fmaf(y0.y, w0.y, p); p = fmaf(y0.z, w0.z, p); p = fmaf(y0.w, w0.w, p);
        p = fmaf(y1.x, w1.x, p); p = fmaf(y1.y, w1.y, p); p = fmaf(y1.z, w1.z, p); p = fmaf(y1.w, w1.w, p);
        p = fmaf(y2.x, w2.x, p); p = fmaf(y2.y, w2.y, p); p = fmaf(y2.z, w2.z, p); p = fmaf(y2.w, w2.w, p);
        p = fmaf(y3.x, w3.x, p); p = fmaf(y3.y, w3.y, p); p = fmaf(y3.z, w3.z, p); p = fmaf(y3.w, w3.w, p);
        #pragma unroll
        for (int off = 32; off; off >>= 1) p += __shfl_xor(p, off);
        if (lane == 0) feats[(size_t)t * KTAG + j] = p + btag[j];
    }
}

// =====================================================================
// Sequential Viterbi max scan (bit-exact vs reference, no argmax on chain).
// 1 wave. Lane layout: to = lane%24, half = lane/24 covers 12 'from' each.
// fv rows stored to fvstore (slot 0 = init, slot t+1 = fv_t) for bp recompute.
// =====================================================================
__global__ __launch_bounds__(64) void viterbi_scan(
    const float* __restrict__ feats, const float* __restrict__ trans,
    float* __restrict__ fvstore, float* __restrict__ out, int* __restrict__ bestb)
{
    const int lane = threadIdx.x;
    const int to = lane % 24, hh = lane / 24;
    const bool act = hh < 2;
    const int hb = (hh & 1) * 12;

    float tr[12], fvr[12];
    #pragma unroll
    for (int i = 0; i < 12; ++i) tr[i] = act ? trans[to * 24 + hb + i] : -3.0e37f;
    #pragma unroll
    for (int i = 0; i < 12; ++i) fvr[i] = (hb + i == 0) ? 0.0f : NEGV;
    if (lane < 24) fvstore[lane] = (lane == 0) ? 0.0f : NEGV;

    float ftc = (lane < 24) ? feats[lane] : 0.0f;
    const int partner = act ? (to + ((hh ^ 1) * 24)) : lane;
    float fvnew = 0.0f;

    for (int t = 0; t < SEQ; ++t) {
        const float ftn = (lane < 24 && t + 1 < SEQ) ? feats[(size_t)(t + 1) * KTAG + lane] : 0.0f;
        float v0  = fvr[0]  + tr[0],  v1  = fvr[1]  + tr[1];
        float v2  = fvr[2]  + tr[2],  v3  = fvr[3]  + tr[3];
        float v4  = fvr[4]  + tr[4],  v5  = fvr[5]  + tr[5];
        float v6  = fvr[6]  + tr[6],  v7  = fvr[7]  + tr[7];
        float v8  = fvr[8]  + tr[8],  v9  = fvr[9]  + tr[9];
        float v10 = fvr[10] + tr[10], v11 = fvr[11] + tr[11];
        float m = fmaxf(fmaxf(fmaxf(v0, v1), fmaxf(v2, v3)),
                        fmaxf(fmaxf(v4, v5), fmaxf(v6, v7)));
        m = fmaxf(m, fmaxf(fmaxf(v8, v9), fmaxf(v10, v11)));
        m = fmaxf(m, __shfl(m, partner));
        fvnew = m + ftc;                 // valid on lanes < 24
        if (lane < 24) fvstore[(size_t)(t + 1) * KTAG + lane] = fvnew;
        #pragma unroll
        for (int i = 0; i < 12; ++i) fvr[i] = __shfl(fvnew, hb + i);   // re-replicate
        ftc = ftn;
    }

    // terminal
    float val = -3.0e38f; int idx = lane;
    if (lane < 24) {
        val = fvnew + trans[1 * 24 + lane];          // transitions[STOP][from]
        if (lane == 0 || lane == 1) val = NEGV;      // exclude START, STOP
    }
    #pragma unroll
    for (int off = 16; off; off >>= 1) {
        const float ov = __shfl_xor(val, off);
        const int   oi = __shfl_xor(idx, off);
        if (ov > val || (ov == val && oi < idx)) { val = ov; idx = oi; }
    }
    if (lane == 0) { out[0] = val; *bestb = idx; }
}

// =====================================================================
// Recompute backpointers in parallel: bp[t][to] = argmax_from(fv_{t-1}[from]+trans)
// Identical fp32 adds + first-index tie rule -> matches the sequential scan.
// =====================================================================
__global__ __launch_bounds__(256) void bp_kernel(
    const float* __restrict__ fvstore, const float* __restrict__ trans, uint8_t* __restrict__ bp)
{
    const int idx = blockIdx.x * 256 + threadIdx.x;
    const int t = idx / KTAG, to = idx % KTAG;
    const float* fv = fvstore + (size_t)t * KTAG;   // slot t = fv_{t-1}
    const float* tr = trans + to * 24;
    float m = fv[0] + tr[0]; int bi = 0;
    #pragma unroll
    for (int f = 1; f < 24; ++f) {
        const float v = fv[f] + tr[f];
        if (v > m) { m = v; bi = f; }
    }
    bp[idx] = (uint8_t)bi;
}

// =====================================================================
// Parallel backtrace via exact integer map composition over 64-step chunks.
// =====================================================================
__global__ __launch_bounds__(1024) void backtrace_kernel(
    const uint8_t* __restrict__ bp, const int* __restrict__ bestb, float* __restrict__ out)
{
    __shared__ uint8_t E[64][24];
    __shared__ uint8_t tops[64];
    const int tid = threadIdx.x;
    const int wv = tid >> 6, lane = tid & 63;

    // phase 1: chunk maps E_c: top_c -> top_{c-1} (applies bp[64c+63] .. bp[64c])
    for (int ci = 0; ci < 4; ++ci) {
        const int ck = wv * 4 + ci;
        if (lane < 24) {
            int y = lane;
            for (int k = 63; k >= 0; --k) y = bp[(size_t)(ck * 64 + k) * KTAG + y];
            E[ck][lane] = (uint8_t)y;
        }
    }
    __syncthreads();

    // phase 2: serial fold over 64 chunk maps
    if (tid == 0) {
        int topc = *bestb;
        tops[63] = (uint8_t)topc;
        for (int ck = 63; ck >= 1; --ck) { topc = E[ck][topc]; tops[ck - 1] = (uint8_t)topc; }
    }
    __syncthreads();

    // phase 3: fill each chunk
    for (int ci = 0; ci < 4; ++ci) {
        const int ck = wv * 4 + ci;
        if (lane == 0) {
            int y = tops[ck];
            out[1 + ck * 64 + 63] = (float)y;
            for (int tt = ck * 64 + 62; tt >= ck * 64; --tt) {
                y = bp[(size_t)(tt + 1) * KTAG + y];
                out[1 + tt] = (float)y;
            }
        }
    }
}

// =====================================================================
extern "C" void kernel_launch(void* const* d_in, const int* in_sizes, int n_in,
                              void* d_out, int out_size, void* d_ws, size_t ws_size,
                              hipStream_t stream)
{
    (void)in_sizes; (void)n_in; (void)out_size; (void)ws_size;
    // Inputs in setup_inputs() dict INSERTION order: transitions is added
    // LAST (after h0/c0), even though the reference signature lists it earlier.
    const float* X     = (const float*)d_in[0];
    const float* Wih0f = (const float*)d_in[1];
    const float* Whh0f = (const float*)d_in[2];
    const float* b0f   = (const float*)d_in[3];
    const float* Wih0b = (const float*)d_in[4];
    const float* Whh0b = (const float*)d_in[5];
    const float* b0b   = (const float*)d_in[6];
    const float* Wih1f = (const float*)d_in[7];
    const float* Whh1f = (const float*)d_in[8];
    const float* b1f   = (const float*)d_in[9];
    const float* Wih1b = (const float*)d_in[10];
    const float* Whh1b = (const float*)d_in[11];
    const float* b1b   = (const float*)d_in[12];
    const float* Wtag  = (const float*)d_in[13];
    const float* btag  = (const float*)d_in[14];
    const float* h0    = (const float*)d_in[15];
    const float* c0    = (const float*)d_in[16];
    const float* trans = (const float*)d_in[17];
    float* out = (float*)d_out;

    // workspace carve-up (floats)
    float* f   = (float*)d_ws;
    float* Pf  = f;                                   // SEQ*2048
    float* Pb  = Pf  + (size_t)SEQ * G4H;             // SEQ*2048
    float* hf0 = Pb  + (size_t)SEQ * G4H;             // (SEQ+1)*512 each
    float* hb0 = hf0 + (size_t)(SEQ + 1) * HID;
    float* hf1 = hb0 + (size_t)(SEQ + 1) * HID;
    float* hb1 = hf1 + (size_t)(SEQ + 1) * HID;
    float* feats = hb1 + (size_t)(SEQ + 1) * HID;     // SEQ*24
    float* fvst  = feats + (size_t)SEQ * KTAG;        // (SEQ+1)*24
    int*   bestb = (int*)(fvst + (size_t)(SEQ + 1) * KTAG);
    uint8_t* bp  = (uint8_t*)(bestb + 4);             // SEQ*24 bytes

    // NaN-sentinel fill for all 4 hist buffers (sync mechanism for the LSTM)
    hipMemsetAsync(hf0, 0xFF, (size_t)4 * (SEQ + 1) * HID * sizeof(float), stream);

    // layer 0: input projection, then persistent bidirectional recurrence
    gemm_proj<<<dim3(SEQ / 128, G4H / 128, 2), 256, 0, stream>>>(
        X, nullptr, nullptr, DIN, 0, Wih0f, b0f, Pf, Wih0b, b0b, Pb);
    lstm_layer<<<64, 512, 0, stream>>>(Pf, Pb, Whh0f, Whh0b, h0, c0, 0, hf0, hb0);

    // layer 1 (P buffers reused; layer-0 input y0 read straight from hist)
    gemm_proj<<<dim3(SEQ / 128, G4H / 128, 2), 256, 0, stream>>>(
        nullptr, hf0, hb0, 1024, 1, Wih1f, b1f, Pf, Wih1b, b1b, Pb);
    lstm_layer<<<64, 512, 0, stream>>>(Pf, Pb, Whh1f, Whh1b, h0, c0, 2, hf1, hb1);

    // tag head + Viterbi
    feats_kernel<<<SEQ / 4, 256, 0, stream>>>(hf1, hb1, Wtag, btag, feats);
    viterbi_scan<<<1, 64, 0, stream>>>(feats, trans, fvst, out, bestb);
    bp_kernel<<<(SEQ * KTAG) / 256, 256, 0, stream>>>(fvst, trans, bp);
    backtrace_kernel<<<1, 1024, 0, stream>>>(bp, bestb, out);
}

// Round 13
// 16495.847 us; speedup vs baseline: 1.3880x; 1.0749x over previous
//
#include <hip/hip_runtime.h>
#include <hip/hip_bf16.h>
#include <stdint.h>
#include <math.h>

// Problem dims
constexpr int SEQ  = 4096;
constexpr int DIN  = 1152;
constexpr int HID  = 512;
constexpr int G4H  = 2048;   // 4*HID
constexpr int KTAG = 24;
constexpr float NEGV = -10000.0f;

__device__ __forceinline__ float sigm(float x) { return 1.0f / (1.0f + expf(-x)); }

// =====================================================================
// GEMM: C[SEQ][2048] = A[SEQ][KA] @ W[2048][KA]^T + b   (fp32, 128x128 tile,
// 8x8 per thread, K-step 16, DOUBLE-BUFFERED LDS: one barrier per K-slab,
// global loads for slab k+1 issued under compute of slab k).
// Per-element accumulation is a single fmaf chain in strictly ascending k
// with bias added last -> BIT-EXACT with the original tiling (absmax 0.0).
// =====================================================================
__global__ __launch_bounds__(256) void gemm_proj(
    const float* __restrict__ A, const float* __restrict__ hf, const float* __restrict__ hb,
    int KA, int mode,
    const float* __restrict__ Wf, const float* __restrict__ bf, float* __restrict__ Cf,
    const float* __restrict__ Wb, const float* __restrict__ bb, float* __restrict__ Cb)
{
    const float* W    = blockIdx.z ? Wb : Wf;
    const float* bias = blockIdx.z ? bb : bf;
    float*       C    = blockIdx.z ? Cb : Cf;

    __shared__ __align__(16) float As[2][16][132];   // [buf][k][m], pad 132
    __shared__ __align__(16) float Ws[2][16][144];   // [buf][k][pos(n)], bank-spread

    const int tid  = threadIdx.x;
    const int bm   = blockIdx.x * 128;
    const int bn   = blockIdx.y * 128;
    const int lrow = tid >> 1;            // 0..127
    const int kq   = (tid & 1) * 8;       // 0 or 8
    const int tx   = tid & 15;            // col block (8 wide)
    const int ty   = tid >> 4;            // row block (8 tall)
    const int wpos = lrow + 4 * (lrow >> 5);        // Ws write position
    const int bpos = tx * 8 + 4 * (tx >> 2);        // Ws read position

    float acc[8][8] = {};
    float4 a0, a1, w0, w1;

    // load slab 0 into registers
    {
        const int k0 = kq;
        if (mode == 0) {
            const float* p = A + (size_t)(bm + lrow) * KA + k0;
            a0 = *(const float4*)p; a1 = *(const float4*)(p + 4);
        } else {
            const int arow = bm + lrow;
            const float* p0 = (k0 < 512) ? (hf + (size_t)(arow + 1) * HID + k0)
                                         : (hb + (size_t)(SEQ - arow) * HID + (k0 - 512));
            const int k1 = k0 + 4;
            const float* p1 = (k1 < 512) ? (hf + (size_t)(arow + 1) * HID + k1)
                                         : (hb + (size_t)(SEQ - arow) * HID + (k1 - 512));
            a0 = *(const float4*)p0; a1 = *(const float4*)p1;
        }
        const float* qp = W + (size_t)(bn + lrow) * KA + k0;
        w0 = *(const float4*)qp; w1 = *(const float4*)(qp + 4);
    }

    int buf = 0;
    for (int bk = 0; bk < KA; bk += 16) {
        // stage current slab regs -> LDS[buf]
        As[buf][kq+0][lrow] = a0.x; As[buf][kq+1][lrow] = a0.y; As[buf][kq+2][lrow] = a0.z; As[buf][kq+3][lrow] = a0.w;
        As[buf][kq+4][lrow] = a1.x; As[buf][kq+5][lrow] = a1.y; As[buf][kq+6][lrow] = a1.z; As[buf][kq+7][lrow] = a1.w;
        Ws[buf][kq+0][wpos] = w0.x; Ws[buf][kq+1][wpos] = w0.y; Ws[buf][kq+2][wpos] = w0.z; Ws[buf][kq+3][wpos] = w0.w;
        Ws[buf][kq+4][wpos] = w1.x; Ws[buf][kq+5][wpos] = w1.y; Ws[buf][kq+6][wpos] = w1.z; Ws[buf][kq+7][wpos] = w1.w;
        __syncthreads();                 // LDS[buf] ready (single barrier per slab)

        // issue next slab's global loads (overlap with compute below)
        if (bk + 16 < KA) {
            const int k0 = bk + 16 + kq;
            if (mode == 0) {
                const float* p = A + (size_t)(bm + lrow) * KA + k0;
                a0 = *(const float4*)p; a1 = *(const float4*)(p + 4);
            } else {
                const int arow = bm + lrow;
                const float* p0 = (k0 < 512) ? (hf + (size_t)(arow + 1) * HID + k0)
                                             : (hb + (size_t)(SEQ - arow) * HID + (k0 - 512));
                const int k1 = k0 + 4;
                const float* p1 = (k1 < 512) ? (hf + (size_t)(arow + 1) * HID + k1)
                                             : (hb + (size_t)(SEQ - arow) * HID + (k1 - 512));
                a0 = *(const float4*)p0; a1 = *(const float4*)p1;
            }
            const float* qp = W + (size_t)(bn + lrow) * KA + k0;
            w0 = *(const float4*)qp; w1 = *(const float4*)(qp + 4);
        }

        #pragma unroll
        for (int kk = 0; kk < 16; ++kk) {
            const float4 av0 = *(const float4*)&As[buf][kk][ty * 8];
            const float4 av1 = *(const float4*)&As[buf][kk][ty * 8 + 4];
            const float4 bv0 = *(const float4*)&Ws[buf][kk][bpos];
            const float4 bv1 = *(const float4*)&Ws[buf][kk][bpos + 4];
            const float a8[8] = {av0.x, av0.y, av0.z, av0.w, av1.x, av1.y, av1.z, av1.w};
            const float b8[8] = {bv0.x, bv0.y, bv0.z, bv0.w, bv1.x, bv1.y, bv1.z, bv1.w};
            #pragma unroll
            for (int i = 0; i < 8; ++i)
                #pragma unroll
                for (int j = 0; j < 8; ++j)
                    acc[i][j] = fmaf(a8[i], b8[j], acc[i][j]);
        }
        buf ^= 1;
        // no second barrier: fast threads write the OTHER buffer next slab;
        // reads of that buffer finished before the barrier all threads passed.
    }

    const float4 bx0 = *(const float4*)&bias[bn + tx * 8];
    const float4 bx1 = *(const float4*)&bias[bn + tx * 8 + 4];
    #pragma unroll
    for (int im = 0; im < 8; ++im) {
        float4 o0, o1;
        o0.x = acc[im][0] + bx0.x; o0.y = acc[im][1] + bx0.y;
        o0.z = acc[im][2] + bx0.z; o0.w = acc[im][3] + bx0.w;
        o1.x = acc[im][4] + bx1.x; o1.y = acc[im][5] + bx1.y;
        o1.z = acc[im][6] + bx1.z; o1.w = acc[im][7] + bx1.w;
        float* cp = &C[(size_t)(bm + ty * 8 + im) * G4H + bn + tx * 8];
        *(float4*)cp = o0;
        *(float4*)(cp + 4) = o1;
    }
}

// =====================================================================
// Persistent bidirectional LSTM layer, v12 = v9 + OPAQUE-ONE WEIGHT
// RESIDENCY.
// v11's clean null closed the "which memory" question: conflict-free LDS
// weights (256KB/step @ ~112B/cy/CU ~ 2300cy) == L2 weights (128KB @
// ~60B/cy ~ 2200cy). The stream itself must go away -> true VGPR
// residency (64 floats/thread, fits easily at 2 waves/SIMD = 256 VGPR
// budget). The compiler remats pure loop-invariant loads at the use
// site (v9: VGPR=56); asm pins spill (v5) or get ignored (v8b).
// Fix: multiply each weight by `one` — a KERNEL ARGUMENT equal to 1.0f
// (runtime SGPR, opaque to the compiler). w*1.0f is IEEE bit-identity
// (incl. -0.0/denorms) -> FMA chain bit-exact; but the products are now
// runtime-computed values the allocator cannot rematerialize -> they
// stay in VGPRs. Diagnostic: VGPR_Count >= ~130 = success; ~56 = failed.
// If resident: matvec = 16 conflict-free h ds_read_b128 + 64 FMAs
// (~500cy vs ~2200cy stream) and the per-step L2/LLC weight traffic
// disappears (FETCH_SIZE collapse expected).
// Everything else = v9 verbatim: part[]-scatter/wave0-gather reduce,
// v6 tight poll, zP pipelined one step ahead, single 64B hist store.
// =====================================================================
__global__ __launch_bounds__(512, 2) void lstm_layer(
    const float* __restrict__ Pf, const float* __restrict__ Pb,
    const float* __restrict__ Whhf, const float* __restrict__ Whhb,
    const float* __restrict__ h0, const float* __restrict__ c0, int h0base,
    float* __restrict__ histf, float* __restrict__ histb, float one)
{
    const int wg  = blockIdx.x;
    const int dir = wg >> 5;            // 0 fwd, 1 bwd (32 WGs each)
    const int w   = wg & 31;            // slice id: units [w*16, w*16+16)
    const float* P    = dir ? Pb : Pf;
    const float* Whh  = dir ? Whhb : Whhf;
    float* histW      = dir ? histb : histf;

    const int tid  = threadIdx.x;              // 0..511
    const int wave = tid >> 6;                 // 0..7
    const int lane = tid & 63;
    const int q    = lane >> 3;                // k-chunk 0..7
    const int rr   = lane & 7;                 // row-in-wave 0..7
    const int g    = wave >> 1;                // gate 0..3 (i,f,g,o)
    const int usub = (wave & 1) * 8;
    const int uu   = usub + rr;                // unit-in-WG 0..15 (this row)
    const int unit = w * 16 + uu;              // global unit [0,512)
    const int grow = g * HID + unit;           // matvec-role z-row [0,2048)
    const int prow = g * 16 + uu;              // part[] row index 0..63

    // reduce-role indices (wave 0 only): lane r handles part row r
    const int gR    = lane >> 4;               // gate of reduced row
    const int uR    = lane & 15;               // unit of reduced row
    const int growR = gR * HID + w * 16 + uR;  // z-row for zP prefetch

    // weights -> named registers, made NON-REMATERIALIZABLE by the
    // opaque multiply (one == 1.0f at runtime; bit-identity).
    const float4* wp = (const float4*)(Whh + (size_t)grow * HID + q * 64);
    float4 w0 = wp[0],  w1 = wp[1],  w2 = wp[2],  w3 = wp[3];
    float4 w4 = wp[4],  w5 = wp[5],  w6 = wp[6],  w7 = wp[7];
    float4 w8 = wp[8],  w9 = wp[9],  wA = wp[10], wB = wp[11];
    float4 wC = wp[12], wD = wp[13], wE = wp[14], wF = wp[15];
    w0.x *= one; w0.y *= one; w0.z *= one; w0.w *= one;
    w1.x *= one; w1.y *= one; w1.z *= one; w1.w *= one;
    w2.x *= one; w2.y *= one; w2.z *= one; w2.w *= one;
    w3.x *= one; w3.y *= one; w3.z *= one; w3.w *= one;
    w4.x *= one; w4.y *= one; w4.z *= one; w4.w *= one;
    w5.x *= one; w5.y *= one; w5.z *= one; w5.w *= one;
    w6.x *= one; w6.y *= one; w6.z *= one; w6.w *= one;
    w7.x *= one; w7.y *= one; w7.z *= one; w7.w *= one;
    w8.x *= one; w8.y *= one; w8.z *= one; w8.w *= one;
    w9.x *= one; w9.y *= one; w9.z *= one; w9.w *= one;
    wA.x *= one; wA.y *= one; wA.z *= one; wA.w *= one;
    wB.x *= one; wB.y *= one; wB.z *= one; wB.w *= one;
    wC.x *= one; wC.y *= one; wC.z *= one; wC.w *= one;
    wD.x *= one; wD.y *= one; wD.z *= one; wD.w *= one;
    wE.x *= one; wE.y *= one; wE.z *= one; wE.w *= one;
    wF.x *= one; wF.y *= one; wF.z *= one; wF.w *= one;

    // cell state on the first 16 threads (one per unit)
    float c = 0.0f;
    if (tid < 16) c = c0[(size_t)(h0base + dir) * HID + w * 16 + tid];

    // padded h: chunk k lives at [k*68, k*68+64); conflict-free broadcast
    __shared__ __align__(16) float hsp[8 * 68];
    __shared__ float part[64][9];

    // initial h into padded LDS
    hsp[(tid >> 6) * 68 + (tid & 63)] = h0[(size_t)(h0base + dir) * HID + tid];
    __syncthreads();

    // zP for step 0; thereafter software-pipelined one step ahead.
    // Wave 0 holds zP for ALL 64 rows (lane r -> row r's term).
    float zPc = 0.0f;
    if (wave == 0) zPc = P[(size_t)(dir ? (SEQ - 1) : 0) * G4H + growR];

    for (int s = 0; s < SEQ; ++s) {
        // prefetch NEXT step's input-projection term (off critical path)
        float zPn = 0.0f;
        if (wave == 0 && s + 1 < SEQ) {
            const int tn = dir ? (SEQ - 2 - s) : (s + 1);
            zPn = P[(size_t)tn * G4H + growR];
        }

        // matvec partial: SAME ordered 64-fma chain (weights VGPR-resident)
        float acc = 0.0f;
        {
            const float* hb4 = &hsp[q * 68];
            float4 h4;
            h4 = *(const float4*)&hb4[ 0]; acc = fmaf(w0.x,h4.x,acc); acc = fmaf(w0.y,h4.y,acc); acc = fmaf(w0.z,h4.z,acc); acc = fmaf(w0.w,h4.w,acc);
            h4 = *(const float4*)&hb4[ 4]; acc = fmaf(w1.x,h4.x,acc); acc = fmaf(w1.y,h4.y,acc); acc = fmaf(w1.z,h4.z,acc); acc = fmaf(w1.w,h4.w,acc);
            h4 = *(const float4*)&hb4[ 8]; acc = fmaf(w2.x,h4.x,acc); acc = fmaf(w2.y,h4.y,acc); acc = fmaf(w2.z,h4.z,acc); acc = fmaf(w2.w,h4.w,acc);
            h4 = *(const float4*)&hb4[12]; acc = fmaf(w3.x,h4.x,acc); acc = fmaf(w3.y,h4.y,acc); acc = fmaf(w3.z,h4.z,acc); acc = fmaf(w3.w,h4.w,acc);
            h4 = *(const float4*)&hb4[16]; acc = fmaf(w4.x,h4.x,acc); acc = fmaf(w4.y,h4.y,acc); acc = fmaf(w4.z,h4.z,acc); acc = fmaf(w4.w,h4.w,acc);
            h4 = *(const float4*)&hb4[20]; acc = fmaf(w5.x,h4.x,acc); acc = fmaf(w5.y,h4.y,acc); acc = fmaf(w5.z,h4.z,acc); acc = fmaf(w5.w,h4.w,acc);
            h4 = *(const float4*)&hb4[24]; acc = fmaf(w6.x,h4.x,acc); acc = fmaf(w6.y,h4.y,acc); acc = fmaf(w6.z,h4.z,acc); acc = fmaf(w6.w,h4.w,acc);
            h4 = *(const float4*)&hb4[28]; acc = fmaf(w7.x,h4.x,acc); acc = fmaf(w7.y,h4.y,acc); acc = fmaf(w7.z,h4.z,acc); acc = fmaf(w7.w,h4.w,acc);
            h4 = *(const float4*)&hb4[32]; acc = fmaf(w8.x,h4.x,acc); acc = fmaf(w8.y,h4.y,acc); acc = fmaf(w8.z,h4.z,acc); acc = fmaf(w8.w,h4.w,acc);
            h4 = *(const float4*)&hb4[36]; acc = fmaf(w9.x,h4.x,acc); acc = fmaf(w9.y,h4.y,acc); acc = fmaf(w9.z,h4.z,acc); acc = fmaf(w9.w,h4.w,acc);
            h4 = *(const float4*)&hb4[40]; acc = fmaf(wA.x,h4.x,acc); acc = fmaf(wA.y,h4.y,acc); acc = fmaf(wA.z,h4.z,acc); acc = fmaf(wA.w,h4.w,acc);
            h4 = *(const float4*)&hb4[44]; acc = fmaf(wB.x,h4.x,acc); acc = fmaf(wB.y,h4.y,acc); acc = fmaf(wB.z,h4.z,acc); acc = fmaf(wB.w,h4.w,acc);
            h4 = *(const float4*)&hb4[48]; acc = fmaf(wC.x,h4.x,acc); acc = fmaf(wC.y,h4.y,acc); acc = fmaf(wC.z,h4.z,acc); acc = fmaf(wC.w,h4.w,acc);
            h4 = *(const float4*)&hb4[52]; acc = fmaf(wD.x,h4.x,acc); acc = fmaf(wD.y,h4.y,acc); acc = fmaf(wD.z,h4.z,acc); acc = fmaf(wD.w,h4.w,acc);
            h4 = *(const float4*)&hb4[56]; acc = fmaf(wE.x,h4.x,acc); acc = fmaf(wE.y,h4.y,acc); acc = fmaf(wE.z,h4.z,acc); acc = fmaf(wE.w,h4.w,acc);
            h4 = *(const float4*)&hb4[60]; acc = fmaf(wF.x,h4.x,acc); acc = fmaf(wF.y,h4.y,acc); acc = fmaf(wF.z,h4.z,acc); acc = fmaf(wF.w,h4.w,acc);
        }

        // scatter raw partial (ONE ds_write pre-barrier)
        part[prow][q] = acc;
        __syncthreads();                           // B1: part[] complete

        if (wave == 0) {
            // lane r reduces row r: 8 conflict-free scalar LDS reads
            float p0 = part[lane][0], p1 = part[lane][1];
            float p2 = part[lane][2], p3 = part[lane][3];
            float p4 = part[lane][4], p5 = part[lane][5];
            float p6 = part[lane][6], p7 = part[lane][7];
            // EXACT v1 association: s2_i = c_{2i}+c_{2i+1};
            // z = ((s2_0+s2_1)+s2_2)+s2_3 + zP
            const float s20 = p0 + p1, s21 = p2 + p3;
            const float s22 = p4 + p5, s23 = p6 + p7;
            float z = s20 + s21;
            z += s22;
            z += s23;
            z += zPc;
            // activation (identical functions on identical inputs)
            const float act = (gR == 2) ? tanhf(z) : sigm(z);
            // gather the 4 gates of unit uR
            const float ai = __shfl(act, uR);
            const float af = __shfl(act, 16 + uR);
            const float ag = __shfl(act, 32 + uR);
            const float ao = __shfl(act, 48 + uR);
            if (lane < 16) {
                const float cn = af * c + ai * ag;  // == sigm(zf)*c + sigm(zi)*tanhf(zg)
                const float hv = ao * tanhf(cn);    // == sigm(zo)*tanhf(cn)
                c = cn;
                // 16 lanes x 4B contiguous, 64B-aligned = one write transaction
                __hip_atomic_store(&histW[(size_t)(s + 1) * HID + w * 16 + lane], hv,
                                   __ATOMIC_RELAXED, __HIP_MEMORY_SCOPE_AGENT);
            }
        }
        zPc = zPn;

        if (s + 1 < SEQ) {
            // v6 tight poll (PROVEN): one load outstanding per thread.
            const uint32_t* src = (const uint32_t*)(histW + (size_t)(s + 1) * HID);
            uint32_t A = __hip_atomic_load(&src[tid], __ATOMIC_RELAXED, __HIP_MEMORY_SCOPE_AGENT);
            uint32_t B = __hip_atomic_load(&src[tid], __ATOMIC_RELAXED, __HIP_MEMORY_SCOPE_AGENT);
            while (A == 0xFFFFFFFFu) {
                A = B;
                B = __hip_atomic_load(&src[tid], __ATOMIC_RELAXED, __HIP_MEMORY_SCOPE_AGENT);
            }
            hsp[(tid >> 6) * 68 + (tid & 63)] = __uint_as_float(A);
            __syncthreads();                       // B2: hs[s+1] complete,
                                                   // also fences part[] reuse
        }
    }
}

// =====================================================================
// feats[t][j] = b_tag[j] + sum_k y1[t][k] * Wtag[j][k], y1 from hist buffers.
// One wave per t-row.
// =====================================================================
__global__ __launch_bounds__(256) void feats_kernel(
    const float* __restrict__ hf, const float* __restrict__ hb,
    const float* __restrict__ Wtag, const float* __restrict__ btag, float* __restrict__ feats)
{
    const int wv = threadIdx.x >> 6, lane = threadIdx.x & 63;
    const int t  = blockIdx.x * 4 + wv;
    const int k0 = lane * 16;
    const float* src = (k0 < 512) ? (hf + (size_t)(t + 1) * HID + k0)
                                  : (hb + (size_t)(SEQ - t) * HID + (k0 - 512));
    const float4 y0 = ((const float4*)src)[0];
    const float4 y1 = ((const float4*)src)[1];
    const float4 y2 = ((const float4*)src)[2];
    const float4 y3 = ((const float4*)src)[3];
    for (int j = 0; j < KTAG; ++j) {
        const float4* wp = (const float4*)&Wtag[(size_t)j * 1024 + k0];
        const float4 w0 = wp[0], w1 = wp[1], w2 = wp[2], w3 = wp[3];
        float p = 0.0f;
        p = fmaf(y0.x, w0.x, p); p = fmaf(y0.y, w0.y, p); p = fmaf(y0.z, w0.z, p); p = fmaf(y0.w, w0.w, p);
        p = fmaf(y1.x, w1.x, p); p = fmaf(y1.y, w1.y, p); p = fmaf(y1.z, w1.z, p); p = fmaf(y1.w, w1.w, p);
        p = fmaf(y2.x, w2.x, p); p = fmaf(y2.y, w2.y, p); p = fmaf(y2.z, w2.z, p); p = fmaf(y2.w, w2.w, p);
        p = fmaf(y3.x, w3.x, p); p = fmaf(y3.y, w3.y, p); p = fmaf(y3.z, w3.z, p); p = fmaf(y3.w, w3.w, p);
        #pragma unroll
        for (int off = 32; off; off >>= 1) p += __shfl_xor(p, off);
        if (lane == 0) feats[(size_t)t * KTAG + j] = p + btag[j];
    }
}

// =====================================================================
// Sequential Viterbi max scan (bit-exact vs reference, no argmax on chain).
// 1 wave. Lane layout: to = lane%24, half = lane/24 covers 12 'from' each.
// fv rows stored to fvstore (slot 0 = init, slot t+1 = fv_t) for bp recompute.
// =====================================================================
__global__ __launch_bounds__(64) void viterbi_scan(
    const float* __restrict__ feats, const float* __restrict__ trans,
    float* __restrict__ fvstore, float* __restrict__ out, int* __restrict__ bestb)
{
    const int lane = threadIdx.x;
    const int to = lane % 24, hh = lane / 24;
    const bool act = hh < 2;
    const int hb = (hh & 1) * 12;

    float tr[12], fvr[12];
    #pragma unroll
    for (int i = 0; i < 12; ++i) tr[i] = act ? trans[to * 24 + hb + i] : -3.0e37f;
    #pragma unroll
    for (int i = 0; i < 12; ++i) fvr[i] = (hb + i == 0) ? 0.0f : NEGV;
    if (lane < 24) fvstore[lane] = (lane == 0) ? 0.0f : NEGV;

    float ftc = (lane < 24) ? feats[lane] : 0.0f;
    const int partner = act ? (to + ((hh ^ 1) * 24)) : lane;
    float fvnew = 0.0f;

    for (int t = 0; t < SEQ; ++t) {
        const float ftn = (lane < 24 && t + 1 < SEQ) ? feats[(size_t)(t + 1) * KTAG + lane] : 0.0f;
        float v0  = fvr[0]  + tr[0],  v1  = fvr[1]  + tr[1];
        float v2  = fvr[2]  + tr[2],  v3  = fvr[3]  + tr[3];
        float v4  = fvr[4]  + tr[4],  v5  = fvr[5]  + tr[5];
        float v6  = fvr[6]  + tr[6],  v7  = fvr[7]  + tr[7];
        float v8  = fvr[8]  + tr[8],  v9  = fvr[9]  + tr[9];
        float v10 = fvr[10] + tr[10], v11 = fvr[11] + tr[11];
        float m = fmaxf(fmaxf(fmaxf(v0, v1), fmaxf(v2, v3)),
                        fmaxf(fmaxf(v4, v5), fmaxf(v6, v7)));
        m = fmaxf(m, fmaxf(fmaxf(v8, v9), fmaxf(v10, v11)));
        m = fmaxf(m, __shfl(m, partner));
        fvnew = m + ftc;                 // valid on lanes < 24
        if (lane < 24) fvstore[(size_t)(t + 1) * KTAG + lane] = fvnew;
        #pragma unroll
        for (int i = 0; i < 12; ++i) fvr[i] = __shfl(fvnew, hb + i);   // re-replicate
        ftc = ftn;
    }

    // terminal
    float val = -3.0e38f; int idx = lane;
    if (lane < 24) {
        val = fvnew + trans[1 * 24 + lane];          // transitions[STOP][from]
        if (lane == 0 || lane == 1) val = NEGV;      // exclude START, STOP
    }
    #pragma unroll
    for (int off = 16; off; off >>= 1) {
        const float ov = __shfl_xor(val, off);
        const int   oi = __shfl_xor(idx, off);
        if (ov > val || (ov == val && oi < idx)) { val = ov; idx = oi; }
    }
    if (lane == 0) { out[0] = val; *bestb = idx; }
}

// =====================================================================
// Recompute backpointers in parallel: bp[t][to] = argmax_from(fv_{t-1}[from]+trans)
// Identical fp32 adds + first-index tie rule -> matches the sequential scan.
// =====================================================================
__global__ __launch_bounds__(256) void bp_kernel(
    const float* __restrict__ fvstore, const float* __restrict__ trans, uint8_t* __restrict__ bp)
{
    const int idx = blockIdx.x * 256 + threadIdx.x;
    const int t = idx / KTAG, to = idx % KTAG;
    const float* fv = fvstore + (size_t)t * KTAG;   // slot t = fv_{t-1}
    const float* tr = trans + to * 24;
    float m = fv[0] + tr[0]; int bi = 0;
    #pragma unroll
    for (int f = 1; f < 24; ++f) {
        const float v = fv[f] + tr[f];
        if (v > m) { m = v; bi = f; }
    }
    bp[idx] = (uint8_t)bi;
}

// =====================================================================
// Parallel backtrace via exact integer map composition over 64-step chunks.
// =====================================================================
__global__ __launch_bounds__(1024) void backtrace_kernel(
    const uint8_t* __restrict__ bp, const int* __restrict__ bestb, float* __restrict__ out)
{
    __shared__ uint8_t E[64][24];
    __shared__ uint8_t tops[64];
    const int tid = threadIdx.x;
    const int wv = tid >> 6, lane = tid & 63;

    // phase 1: chunk maps E_c: top_c -> top_{c-1} (applies bp[64c+63] .. bp[64c])
    for (int ci = 0; ci < 4; ++ci) {
        const int ck = wv * 4 + ci;
        if (lane < 24) {
            int y = lane;
            for (int k = 63; k >= 0; --k) y = bp[(size_t)(ck * 64 + k) * KTAG + y];
            E[ck][lane] = (uint8_t)y;
        }
    }
    __syncthreads();

    // phase 2: serial fold over 64 chunk maps
    if (tid == 0) {
        int topc = *bestb;
        tops[63] = (uint8_t)topc;
        for (int ck = 63; ck >= 1; --ck) { topc = E[ck][topc]; tops[ck - 1] = (uint8_t)topc; }
    }
    __syncthreads();

    // phase 3: fill each chunk
    for (int ci = 0; ci < 4; ++ci) {
        const int ck = wv * 4 + ci;
        if (lane == 0) {
            int y = tops[ck];
            out[1 + ck * 64 + 63] = (float)y;
            for (int tt = ck * 64 + 62; tt >= ck * 64; --tt) {
                y = bp[(size_t)(tt + 1) * KTAG + y];
                out[1 + tt] = (float)y;
            }
        }
    }
}

// =====================================================================
extern "C" void kernel_launch(void* const* d_in, const int* in_sizes, int n_in,
                              void* d_out, int out_size, void* d_ws, size_t ws_size,
                              hipStream_t stream)
{
    (void)in_sizes; (void)n_in; (void)out_size; (void)ws_size;
    // Inputs in setup_inputs() dict INSERTION order: transitions is added
    // LAST (after h0/c0), even though the reference signature lists it earlier.
    const float* X     = (const float*)d_in[0];
    const float* Wih0f = (const float*)d_in[1];
    const float* Whh0f = (const float*)d_in[2];
    const float* b0f   = (const float*)d_in[3];
    const float* Wih0b = (const float*)d_in[4];
    const float* Whh0b = (const float*)d_in[5];
    const float* b0b   = (const float*)d_in[6];
    const float* Wih1f = (const float*)d_in[7];
    const float* Whh1f = (const float*)d_in[8];
    const float* b1f   = (const float*)d_in[9];
    const float* Wih1b = (const float*)d_in[10];
    const float* Whh1b = (const float*)d_in[11];
    const float* b1b   = (const float*)d_in[12];
    const float* Wtag  = (const float*)d_in[13];
    const float* btag  = (const float*)d_in[14];
    const float* h0    = (const float*)d_in[15];
    const float* c0    = (const float*)d_in[16];
    const float* trans = (const float*)d_in[17];
    float* out = (float*)d_out;

    // workspace carve-up (floats)
    float* f   = (float*)d_ws;
    float* Pf  = f;                                   // SEQ*2048
    float* Pb  = Pf  + (size_t)SEQ * G4H;             // SEQ*2048
    float* hf0 = Pb  + (size_t)SEQ * G4H;             // (SEQ+1)*512 each
    float* hb0 = hf0 + (size_t)(SEQ + 1) * HID;
    float* hf1 = hb0 + (size_t)(SEQ + 1) * HID;
    float* hb1 = hf1 + (size_t)(SEQ + 1) * HID;
    float* feats = hb1 + (size_t)(SEQ + 1) * HID;     // SEQ*24
    float* fvst  = feats + (size_t)SEQ * KTAG;        // (SEQ+1)*24
    int*   bestb = (int*)(fvst + (size_t)(SEQ + 1) * KTAG);
    uint8_t* bp  = (uint8_t*)(bestb + 4);             // SEQ*24 bytes

    // NaN-sentinel fill for all 4 hist buffers (sync mechanism for the LSTM)
    hipMemsetAsync(hf0, 0xFF, (size_t)4 * (SEQ + 1) * HID * sizeof(float), stream);

    // layer 0: input projection, then persistent bidirectional recurrence
    gemm_proj<<<dim3(SEQ / 128, G4H / 128, 2), 256, 0, stream>>>(
        X, nullptr, nullptr, DIN, 0, Wih0f, b0f, Pf, Wih0b, b0b, Pb);
    lstm_layer<<<64, 512, 0, stream>>>(Pf, Pb, Whh0f, Whh0b, h0, c0, 0, hf0, hb0, 1.0f);

    // layer 1 (P buffers reused; layer-0 input y0 read straight from hist)
    gemm_proj<<<dim3(SEQ / 128, G4H / 128, 2), 256, 0, stream>>>(
        nullptr, hf0, hb0, 1024, 1, Wih1f, b1f, Pf, Wih1b, b1b, Pb);
    lstm_layer<<<64, 512, 0, stream>>>(Pf, Pb, Whh1f, Whh1b, h0, c0, 2, hf1, hb1, 1.0f);

    // tag head + Viterbi
    feats_kernel<<<SEQ / 4, 256, 0, stream>>>(hf1, hb1, Wtag, btag, feats);
    viterbi_scan<<<1, 64, 0, stream>>>(feats, trans, fvst, out, bestb);
    bp_kernel<<<(SEQ * KTAG) / 256, 256, 0, stream>>>(fvst, trans, bp);
    backtrace_kernel<<<1, 1024, 0, stream>>>(bp, bestb, out);
}